// Round 5
// baseline (473.958 us; speedup 1.0000x reference)
//
#include <hip/hip_runtime.h>
#include <hip/hip_bf16.h>
#include <math.h>

// ---------------------------------------------------------------------------
// Qwen3 attention block: T=4096, HIDDEN=2048, 16 Q heads, 8 KV heads,
// HEAD_DIM=128, rope theta 1e6, rms eps 1e-6, causal.
// fp32 in/out; bf16 internally for MFMA with fp32 accumulation.
// ---------------------------------------------------------------------------

typedef __bf16 bf16;
typedef __bf16 bf16x4 __attribute__((ext_vector_type(4)));
typedef __bf16 bf16x8 __attribute__((ext_vector_type(8)));
typedef float  f32x4  __attribute__((ext_vector_type(4)));

__device__ __forceinline__ f32x4 mfma16(bf16x8 a, bf16x8 b, f32x4 c) {
  return __builtin_amdgcn_mfma_f32_16x16x32_bf16(a, b, c, 0, 0, 0);
}

// 4 chained 16x16x16 bf16 MFMAs accumulating into one C/D quad.
__device__ __forceinline__ void mfma16x16_chain4(const bf16x4& a0, const bf16x4& a1,
                                                 const bf16x4& a2, const bf16x4& a3,
                                                 const bf16x4& b0, const bf16x4& b1,
                                                 const bf16x4& b2, const bf16x4& b3,
                                                 f32x4& c) {
  asm volatile(
      "s_nop 2\n\t"
      "v_mfma_f32_16x16x16_bf16 %0, %1, %5, %0\n\t"
      "v_mfma_f32_16x16x16_bf16 %0, %2, %6, %0\n\t"
      "v_mfma_f32_16x16x16_bf16 %0, %3, %7, %0\n\t"
      "v_mfma_f32_16x16x16_bf16 %0, %4, %8, %0"
      : "+v"(c)
      : "v"(a0), "v"(a1), "v"(a2), "v"(a3),
        "v"(b0), "v"(b1), "v"(b2), "v"(b3));
}

// Async global->LDS DMA, 16B per lane. LDS dest is wave-uniform base +
// lane*16 (hardware rule); global src is per-lane.
__device__ __forceinline__ void gload_lds16(const bf16* g, bf16* l) {
  __builtin_amdgcn_global_load_lds(
      (const __attribute__((address_space(1))) unsigned int*)g,
      (__attribute__((address_space(3))) unsigned int*)l, 16, 0, 0);
}

__device__ __forceinline__ void store_c(float* p, float v) { *p = v; }
__device__ __forceinline__ void store_c(bf16* p, float v) { *p = (bf16)v; }

// ---------------------------------------------------------------------------
// fp32 -> bf16 cast, 8 elems/thread
// ---------------------------------------------------------------------------
__global__ __launch_bounds__(256) void cast_bf16(const float* __restrict__ s,
                                                 bf16* __restrict__ d) {
  int i = blockIdx.x * 256 + threadIdx.x;
  float4 a = reinterpret_cast<const float4*>(s)[i * 2];
  float4 b = reinterpret_cast<const float4*>(s)[i * 2 + 1];
  bf16x8 v = {(bf16)a.x, (bf16)a.y, (bf16)a.z, (bf16)a.w,
              (bf16)b.x, (bf16)b.y, (bf16)b.z, (bf16)b.w};
  reinterpret_cast<bf16x8*>(d)[i] = v;
}

// ---------------------------------------------------------------------------
// gemm256 — unchanged from R3 (no counter data to attribute a change yet;
// attn speedup this round will surface the GEMM dispatches in top-5).
// ---------------------------------------------------------------------------
__global__ __launch_bounds__(512, 2) void gemm256(const bf16* __restrict__ A,
                                                  const bf16* __restrict__ B,
                                                  bf16* __restrict__ C,
                                                  int M, int N, int K) {
  __shared__ __align__(16) bf16 As[3][256 * 32];
  __shared__ __align__(16) bf16 Bs[3][256 * 32];

  const int tid  = threadIdx.x;
  const int lane = tid & 63;
  const int wid  = tid >> 6;
  const int quad = lane >> 4, l16 = lane & 15;
  const int wr = wid >> 2, wc = wid & 3;  // 2 M-waves x 4 N-waves

  const int nbx = N >> 8;
  const int nwg = (M >> 8) * nbx;
  const int cpx = nwg >> 3;
  const int swz = (blockIdx.x & 7) * cpx + (blockIdx.x >> 3);
  const int m0 = (swz / nbx) << 8;
  const int n0 = (swz % nbx) << 8;

  const int srow = tid >> 2, scol = (tid & 3) * 8;
  const bf16* aSrc0 = &A[(size_t)(m0 + srow) * K + scol];
  const bf16* aSrc1 = &A[(size_t)(m0 + 128 + srow) * K + scol];
  const bf16* bSrc0 = &B[(size_t)(n0 + srow) * K + scol];
  const bf16* bSrc1 = &B[(size_t)(n0 + 128 + srow) * K + scol];

  const f32x4 zero = {0.f, 0.f, 0.f, 0.f};
  f32x4 acc[8][4];
#pragma unroll
  for (int i = 0; i < 8; ++i)
#pragma unroll
    for (int j = 0; j < 4; ++j) acc[i][j] = zero;

  const int NT = K >> 5;

  {
    gload_lds16(aSrc0, &As[0][tid * 8]);
    gload_lds16(aSrc1, &As[0][4096 + tid * 8]);
    gload_lds16(bSrc0, &Bs[0][tid * 8]);
    gload_lds16(bSrc1, &Bs[0][4096 + tid * 8]);
    gload_lds16(aSrc0 + 32, &As[1][tid * 8]);
    gload_lds16(aSrc1 + 32, &As[1][4096 + tid * 8]);
    gload_lds16(bSrc0 + 32, &Bs[1][tid * 8]);
    gload_lds16(bSrc1 + 32, &Bs[1][4096 + tid * 8]);
  }

  int bufC = 0;
  for (int t = 0; t < NT; ++t) {
    if (t == NT - 1) {
      asm volatile("s_waitcnt vmcnt(0)" ::: "memory");
    } else {
      asm volatile("s_waitcnt vmcnt(4)" ::: "memory");
    }
    __builtin_amdgcn_s_barrier();
    __builtin_amdgcn_sched_barrier(0);

    if (t + 2 < NT) {
      int bs = bufC + 2; if (bs >= 3) bs -= 3;
      const int k0 = (t + 2) * 32;
      gload_lds16(aSrc0 + k0, &As[bs][tid * 8]);
      gload_lds16(aSrc1 + k0, &As[bs][4096 + tid * 8]);
      gload_lds16(bSrc0 + k0, &Bs[bs][tid * 8]);
      gload_lds16(bSrc1 + k0, &Bs[bs][4096 + tid * 8]);
    }

    const bf16* AsL = As[bufC];
    const bf16* BsL = Bs[bufC];
    bf16x8 af[8], bfv[4];
#pragma unroll
    for (int fm = 0; fm < 8; ++fm)
      af[fm] = *reinterpret_cast<const bf16x8*>(
          &AsL[(wr * 128 + fm * 16 + l16) * 32 + quad * 8]);
#pragma unroll
    for (int fn = 0; fn < 4; ++fn)
      bfv[fn] = *reinterpret_cast<const bf16x8*>(
          &BsL[(wc * 64 + fn * 16 + l16) * 32 + quad * 8]);
#pragma unroll
    for (int fm = 0; fm < 8; ++fm)
#pragma unroll
      for (int fn = 0; fn < 4; ++fn)
        acc[fm][fn] = mfma16(af[fm], bfv[fn], acc[fm][fn]);

    bufC = bufC + 1 == 3 ? 0 : bufC + 1;
  }

#pragma unroll
  for (int fm = 0; fm < 8; ++fm)
#pragma unroll
    for (int fn = 0; fn < 4; ++fn)
#pragma unroll
      for (int r = 0; r < 4; ++r) {
        int row = m0 + wr * 128 + fm * 16 + quad * 4 + r;
        int col = n0 + wc * 64 + fn * 16 + l16;
        C[(size_t)row * N + col] = (bf16)acc[fm][fn][r];
      }
}

// ---------------------------------------------------------------------------
// gemm_bt v3 (verified): 128x128 tile, 2-phase dbuf, gload_lds staging.
// ---------------------------------------------------------------------------
__device__ __forceinline__ void gemm_step(const bf16* AsL, const bf16* BsL,
                                          int wm, int wn, int l16, int quad,
                                          f32x4 (&acc)[4][4]) {
  bf16x8 af[4], bfr[4];
#pragma unroll
  for (int i = 0; i < 4; ++i)
    af[i] = *reinterpret_cast<const bf16x8*>(&AsL[(wm + i * 16 + l16) * 32 + quad * 8]);
#pragma unroll
  for (int j = 0; j < 4; ++j)
    bfr[j] = *reinterpret_cast<const bf16x8*>(&BsL[(wn + j * 16 + l16) * 32 + quad * 8]);
#pragma unroll
  for (int i = 0; i < 4; ++i)
#pragma unroll
    for (int j = 0; j < 4; ++j)
      acc[i][j] = mfma16(af[i], bfr[j], acc[i][j]);
}

template <typename TC>
__global__ __launch_bounds__(256, 4) void gemm_bt(const bf16* __restrict__ A,
                                                  const bf16* __restrict__ B,
                                                  TC* __restrict__ C,
                                                  int M, int N, int K) {
  __shared__ __align__(16) bf16 As[2][128 * 32];
  __shared__ __align__(16) bf16 Bs[2][128 * 32];

  const int tid  = threadIdx.x;
  const int wave = tid >> 6, lane = tid & 63;
  const int quad = lane >> 4, l16 = lane & 15;
  const int wm = (wave >> 1) * 64, wn = (wave & 1) * 64;
  const int n0 = blockIdx.x * 128, m0 = blockIdx.y * 128;

  const int r0 = tid >> 2;
  const int c0 = (tid & 3) * 8;
  const size_t aBase = (size_t)(m0 + r0) * K + c0;
  const size_t bBase = (size_t)(n0 + r0) * K + c0;
  const size_t rowK64 = (size_t)64 * K;

  const f32x4 zero = {0.f, 0.f, 0.f, 0.f};
  f32x4 acc[4][4];
#pragma unroll
  for (int i = 0; i < 4; ++i)
#pragma unroll
    for (int j = 0; j < 4; ++j) acc[i][j] = zero;

  gload_lds16(&A[aBase],          &As[0][tid * 8]);
  gload_lds16(&A[aBase + rowK64], &As[0][2048 + tid * 8]);
  gload_lds16(&B[bBase],          &Bs[0][tid * 8]);
  gload_lds16(&B[bBase + rowK64], &Bs[0][2048 + tid * 8]);
  __syncthreads();

  int cur = 0;
  for (int k0 = 32; k0 < K; k0 += 32) {
    const int nb = cur ^ 1;
    gload_lds16(&A[aBase + k0],          &As[nb][tid * 8]);
    gload_lds16(&A[aBase + rowK64 + k0], &As[nb][2048 + tid * 8]);
    gload_lds16(&B[bBase + k0],          &Bs[nb][tid * 8]);
    gload_lds16(&B[bBase + rowK64 + k0], &Bs[nb][2048 + tid * 8]);

    gemm_step(As[cur], Bs[cur], wm, wn, l16, quad, acc);

    __syncthreads();
    cur = nb;
  }
  gemm_step(As[cur], Bs[cur], wm, wn, l16, quad, acc);

#pragma unroll
  for (int i = 0; i < 4; ++i)
#pragma unroll
    for (int j = 0; j < 4; ++j)
#pragma unroll
      for (int r = 0; r < 4; ++r) {
        int row = m0 + wm + i * 16 + quad * 4 + r;
        int col = n0 + wn + j * 16 + l16;
        store_c(&C[(size_t)row * N + col], acc[i][j][r]);
      }
}

// ---------------------------------------------------------------------------
// norm_rope v2 — unchanged from R3
// ---------------------------------------------------------------------------
__global__ __launch_bounds__(256) void norm_rope(const bf16* __restrict__ qkv,
                                                 const float* __restrict__ qw,
                                                 const float* __restrict__ kw,
                                                 const int* __restrict__ pos,
                                                 bf16* __restrict__ qn,
                                                 bf16* __restrict__ kn) {
  const int t = blockIdx.x;
  const int wv = threadIdx.x >> 6, l = threadIdx.x & 63;

  float inv = exp2f((float)l * (-19.93156856932417f / 64.0f));
  float fr = (float)pos[t] * inv;
  float sn, cs;
  sincosf(fr, &sn, &cs);
  const float qw1 = qw[l], qw2 = qw[l + 64];
  const float kw1 = kw[l], kw2 = kw[l + 64];
  const size_t rowb = (size_t)t * 4096;

#pragma unroll
  for (int i = 0; i < 6; ++i) {
    const int h = wv * 6 + i;            // 0..23, uniform per wave
    const bool isq = h < 16;
    const int col = isq ? h * 128 : 2048 + (h - 16) * 128;
    float x1 = (float)qkv[rowb + col + l];
    float x2 = (float)qkv[rowb + col + l + 64];
    float ss = x1 * x1 + x2 * x2;
#pragma unroll
    for (int o = 32; o >= 1; o >>= 1) ss += __shfl_xor(ss, o);
    float rms = rsqrtf(ss * (1.0f / 128.0f) + 1e-6f);
    float w1 = isq ? qw1 : kw1, w2 = isq ? qw2 : kw2;
    float xn1 = x1 * rms * w1, xn2 = x2 * rms * w2;
    float o1 = xn1 * cs - xn2 * sn;
    float o2 = xn2 * cs + xn1 * sn;
    if (isq) {
      qn[(size_t)t * 2048 + h * 128 + l] = (bf16)o1;
      qn[(size_t)t * 2048 + h * 128 + l + 64] = (bf16)o2;
    } else {
      kn[(size_t)t * 1024 + (h - 16) * 128 + l] = (bf16)o1;
      kn[(size_t)t * 1024 + (h - 16) * 128 + l + 64] = (bf16)o2;
    }
  }
}

// ---------------------------------------------------------------------------
// One-time V transpose — unchanged
// ---------------------------------------------------------------------------
__global__ __launch_bounds__(256) void transpose_v(const bf16* __restrict__ qkv,
                                                   bf16* __restrict__ vt) {
  __shared__ __align__(16) bf16 tile[128 * 72];
  const int t0 = blockIdx.x * 64, kvh = blockIdx.y;
  const int tid = threadIdx.x;
#pragma unroll
  for (int it = 0; it < 2; ++it) {
    int linear = it * 4096 + tid * 16;
    int r = linear >> 7, c = linear & 127;
    union { uint4 v; bf16 e[8]; } u0, u1;
    u0.v = *reinterpret_cast<const uint4*>(
        &qkv[(size_t)(t0 + r) * 4096 + 3072 + kvh * 128 + c]);
    u1.v = *reinterpret_cast<const uint4*>(
        &qkv[(size_t)(t0 + r) * 4096 + 3072 + kvh * 128 + c + 8]);
#pragma unroll
    for (int j = 0; j < 8; ++j) tile[(c + j) * 72 + r] = u0.e[j];
#pragma unroll
    for (int j = 0; j < 8; ++j) tile[(c + 8 + j) * 72 + r] = u1.e[j];
  }
  __syncthreads();
#pragma unroll
  for (int it = 0; it < 4; ++it) {
    int linear = it * 2048 + tid * 8;
    int d = linear >> 6, c = linear & 63;
    uint4 v = *reinterpret_cast<const uint4*>(&tile[d * 72 + c]);
    *reinterpret_cast<uint4*>(&vt[(size_t)(kvh * 128 + d) * 4096 + t0 + c]) = v;
  }
}

// ---------------------------------------------------------------------------
// Flash attention v9: occupancy restructure.
// R4 counters showed latency-bound: Occupancy 21.5% (2 waves/SIMD), MfmaUtil
// 28, VALUBusy 41, HBM 19% -- no pipe saturated; each wave's serial chain
// exposed. Wave count was structurally pinned: 512 blocks x 4 waves = 2048
// waves = 2/SIMD, and the 64KB double-buffer capped LDS at 2 blocks/CU.
//
// v9 trades the in-wave double-buffer for cross-block TLP:
//   - single-buffered K/V: 32KB/block -> 5 blocks/CU LDS cap
//   - grid (64, 16) = 1024 blocks, one q-tile each, longest-first
//     (qt = 63-bx) so backfill balances (max block 64 units, 130/CU mean)
//   - stage -> sync -> compute -> sync: simplest possible skeleton; the
//     per-tile DMA latency is hidden by the other ~4 resident blocks'
//     compute (m114 implicit wave-level overlap), not by prefetch.
// Inner compute, XOR swizzle, DMA source math byte-identical to v8.
// __launch_bounds__(256,4): 128-VGPR budget (uses ~88; 5/SIMD if <=102).
// ---------------------------------------------------------------------------
__global__ __launch_bounds__(256, 4) void attn(const bf16* __restrict__ q,
                                               const bf16* __restrict__ k,
                                               const bf16* __restrict__ vt,
                                               bf16* __restrict__ out) {
  __shared__ __align__(16) bf16 Ks[64 * 128];  // [kv row][dim] swizzled
  __shared__ __align__(16) bf16 Vs[128 * 64];  // [dim][kv row] swizzled

  const int head = blockIdx.y, kvh = head >> 1;
  const int qt = 63 - (int)blockIdx.x;   // longest-first for backfill balance
  const int q0 = qt * 64;
  const int kend = q0 + 64;

  const int tid = threadIdx.x;
  const int wave = tid >> 6, lane = tid & 63;
  const int quad = lane >> 4, l16 = lane & 15;
  const float cExp = 0.08838834764831845f * 1.4426950408889634f; // scale*log2e
  const f32x4 zero = {0.f, 0.f, 0.f, 0.f};

  // per-lane DMA source offsets (elements), pre-swizzled so the linear
  // LDS write lands in XOR-swizzled layout (identical to v8)
  int kSrc[4], vSrc[4];
#pragma unroll
  for (int it = 0; it < 4; ++it) {
    int r = (wave * 4 + it) * 4 + (lane >> 4);
    kSrc[it] = r * 1024 + kvh * 128 + (((lane & 15) ^ (r & 7)) << 3);
    int d = (wave * 4 + it) * 8 + (lane >> 3);
    vSrc[it] = (kvh * 128 + d) * 4096 + (((lane & 7) ^ (lane >> 3)) << 3);
  }

  // read-side swizzled offsets (row&7 == l16&7 for both K and V reads)
  const int kswz = (l16 & 7) << 3;
  int koff[4], voff[4];
#pragma unroll
  for (int s = 0; s < 4; ++s) {
    koff[s] = (s * 32 + quad * 8) ^ kswz;  // 16B-aligned within 128-elem row
    voff[s] = (s * 16 + quad * 4) ^ kswz;  // 8B-aligned within 64-elem row
  }

  const int qrow = q0 + wave * 16 + l16;

  // Q fragments: B[n=l16][k=s*32+quad*8+j]
  bf16x8 qf[4];
#pragma unroll
  for (int s = 0; s < 4; ++s)
    qf[s] = *reinterpret_cast<const bf16x8*>(
        &q[(size_t)qrow * 2048 + head * 128 + s * 32 + quad * 8]);

  f32x4 o_acc[8];  // O^T: d = dt*16+quad*4+r, q = l16
#pragma unroll
  for (int dt = 0; dt < 8; ++dt) o_acc[dt] = zero;
  float m_i = -3.0e38f, l_i = 0.f;

  for (int k0 = 0; k0 < kend; k0 += 64) {
    // ---- stage this tile (async DMA); barrier's vmcnt(0) drain publishes ----
#pragma unroll
    for (int it = 0; it < 4; ++it) {
      gload_lds16(&k[kSrc[it] + k0 * 1024], &Ks[(wave * 4 + it) * 512]);
      gload_lds16(&vt[vSrc[it] + k0],       &Vs[(wave * 4 + it) * 512]);
    }
    __syncthreads();

    // ---- S^T = K Q^T : rows t (4 tiles of 16), cols q (16) ----
    f32x4 s_acc[4];
    __builtin_amdgcn_s_setprio(1);
#pragma unroll
    for (int mt = 0; mt < 4; ++mt) {
      bf16x8 kf[4];
#pragma unroll
      for (int ks = 0; ks < 4; ++ks)
        kf[ks] = *reinterpret_cast<const bf16x8*>(
            &Ks[(mt * 16 + l16) * 128 + koff[ks]]);
      f32x4 sa = zero;
#pragma unroll
      for (int ks = 0; ks < 4; ++ks) sa = mfma16(kf[ks], qf[ks], sa);
      s_acc[mt] = sa;
    }
    __builtin_amdgcn_s_setprio(0);

    // ---- causal mask (diagonal tile only): t > q -> -inf ----
    if (k0 == q0) {
      int tq = wave * 16 + l16;
#pragma unroll
      for (int mt = 0; mt < 4; ++mt)
#pragma unroll
        for (int r = 0; r < 4; ++r) {
          int tk = mt * 16 + quad * 4 + r;
          if (tk > tq) s_acc[mt][r] = -3.0e38f;
        }
    }

    // ---- online softmax with defer-max (T13) ----
    {
      float mx = -3.0e38f;
#pragma unroll
      for (int mt = 0; mt < 4; ++mt)
#pragma unroll
        for (int r = 0; r < 4; ++r) mx = fmaxf(mx, s_acc[mt][r]);
      mx = fmaxf(mx, __shfl_xor(mx, 16));
      mx = fmaxf(mx, __shfl_xor(mx, 32));
      if (!__all((mx - m_i) * cExp <= 8.0f)) {
        float mn = fmaxf(m_i, mx);
        float al = exp2f((m_i - mn) * cExp);
        m_i = mn;
        l_i *= al;
#pragma unroll
        for (int dt = 0; dt < 8; ++dt)
#pragma unroll
          for (int r = 0; r < 4; ++r) o_acc[dt][r] *= al;
      }
      float nmc = -m_i * cExp;
      float rs = 0.f;
#pragma unroll
      for (int mt = 0; mt < 4; ++mt)
#pragma unroll
        for (int r = 0; r < 4; ++r) {
          float pe = exp2f(fmaf(s_acc[mt][r], cExp, nmc));
          s_acc[mt][r] = pe;
          rs += pe;
        }
      rs += __shfl_xor(rs, 16);
      rs += __shfl_xor(rs, 32);
      l_i += rs;
    }

    // ---- pack P in-register: B[k=t=quad*4+j][n=q=l16] per mt ----
    bf16x4 pb[4];
#pragma unroll
    for (int mt = 0; mt < 4; ++mt) {
      bf16x4 t;
#pragma unroll
      for (int r = 0; r < 4; ++r) t[r] = (bf16)s_acc[mt][r];
      pb[mt] = t;
    }

    // ---- O^T += V^T P via chained 16x16x16 ----
    __builtin_amdgcn_s_setprio(1);
#pragma unroll
    for (int dt = 0; dt < 8; ++dt) {
      const bf16* vrow = &Vs[(dt * 16 + l16) * 64];
      bf16x4 va0 = *reinterpret_cast<const bf16x4*>(&vrow[voff[0]]);
      bf16x4 va1 = *reinterpret_cast<const bf16x4*>(&vrow[voff[1]]);
      bf16x4 va2 = *reinterpret_cast<const bf16x4*>(&vrow[voff[2]]);
      bf16x4 va3 = *reinterpret_cast<const bf16x4*>(&vrow[voff[3]]);
      mfma16x16_chain4(va0, va1, va2, va3, pb[0], pb[1], pb[2], pb[3],
                       o_acc[dt]);
    }
    __builtin_amdgcn_s_setprio(0);

    __syncthreads();  // all waves done reading Ks/Vs before next stage
  }

  // ---- epilogue: O = O^T/l, 4 contiguous d per reg-quad ----
  float rl = __builtin_amdgcn_rcpf(l_i);
#pragma unroll
  for (int dt = 0; dt < 8; ++dt) {
    bf16x4 ov;
#pragma unroll
    for (int r = 0; r < 4; ++r) ov[r] = (bf16)(o_acc[dt][r] * rl);
    *reinterpret_cast<bf16x4*>(
        &out[(size_t)qrow * 2048 + head * 128 + dt * 16 + quad * 4]) = ov;
  }
}

// ---------------------------------------------------------------------------
extern "C" void kernel_launch(void* const* d_in, const int* in_sizes, int n_in,
                              void* d_out, int out_size, void* d_ws, size_t ws_size,
                              hipStream_t stream) {
  const float* hidden = (const float*)d_in[0];
  const float* qkv_w  = (const float*)d_in[1];
  const float* qnw    = (const float*)d_in[2];
  const float* knw    = (const float*)d_in[3];
  const float* o_w    = (const float*)d_in[4];
  const int*   pos    = (const int*)d_in[5];

  bf16* qkv = (bf16*)d_ws;                       // 4096*4096
  bf16* qn  = qkv + (size_t)4096 * 4096;         // 4096*2048
  bf16* kn  = qn  + (size_t)4096 * 2048;         // 4096*1024
  bf16* vt  = kn  + (size_t)4096 * 1024;         // 1024*4096
  bf16* ao  = vt  + (size_t)1024 * 4096;         // 4096*2048
  bf16* hb  = ao;   // bf16 hidden, dead before attn writes ao
  bf16* wq  = kn;   // bf16 qkv_w, dead before norm_rope/transpose write kn/vt
  bf16* wo  = qn;   // bf16 o_w, cast after attn (qn dead)
  float* out = (float*)d_out;

  cast_bf16<<<4096, 256, 0, stream>>>(hidden, hb);
  cast_bf16<<<4096, 256, 0, stream>>>(qkv_w, wq);
  gemm256<<<256, 512, 0, stream>>>(hb, wq, qkv, 4096, 4096, 2048);
  norm_rope<<<4096, 256, 0, stream>>>(qkv, qnw, knw, pos, qn, kn);
  transpose_v<<<dim3(64, 8), 256, 0, stream>>>(qkv, vt);
  attn<<<dim3(64, 16), 256, 0, stream>>>(qn, kn, vt, ao);
  cast_bf16<<<2048, 256, 0, stream>>>(o_w, wo);
  gemm_bt<<<dim3(16, 32), 256, 0, stream>>>(ao, wo, out, 4096, 2048, 2048);
}

// Round 6
// 409.808 us; speedup vs baseline: 1.1565x; 1.1565x over previous
//
#include <hip/hip_runtime.h>
#include <hip/hip_bf16.h>
#include <math.h>

// ---------------------------------------------------------------------------
// Qwen3 attention block: T=4096, HIDDEN=2048, 16 Q heads, 8 KV heads,
// HEAD_DIM=128, rope theta 1e6, rms eps 1e-6, causal.
// fp32 in/out; bf16 internally for MFMA with fp32 accumulation.
//
// R5 = consolidation: attn v8 (R3-verified, 154 us), gemm_bt v3 both GEMMs
// (R2-verified), norm_rope v2 (R3-verified). gemm256 (R3) and attn v9 (R4)
// reverted: gemm256 ~+21us vs v3 (coarse 1-phase schedule, m196 anti-
// pattern); attn v9 +60us (removed in-wave prefetch, occupancy unchanged).
// ---------------------------------------------------------------------------

typedef __bf16 bf16;
typedef __bf16 bf16x4 __attribute__((ext_vector_type(4)));
typedef __bf16 bf16x8 __attribute__((ext_vector_type(8)));
typedef float  f32x4  __attribute__((ext_vector_type(4)));

__device__ __forceinline__ f32x4 mfma16(bf16x8 a, bf16x8 b, f32x4 c) {
  return __builtin_amdgcn_mfma_f32_16x16x32_bf16(a, b, c, 0, 0, 0);
}

// 4 chained 16x16x16 bf16 MFMAs accumulating into one C/D quad.
__device__ __forceinline__ void mfma16x16_chain4(const bf16x4& a0, const bf16x4& a1,
                                                 const bf16x4& a2, const bf16x4& a3,
                                                 const bf16x4& b0, const bf16x4& b1,
                                                 const bf16x4& b2, const bf16x4& b3,
                                                 f32x4& c) {
  asm volatile(
      "s_nop 2\n\t"
      "v_mfma_f32_16x16x16_bf16 %0, %1, %5, %0\n\t"
      "v_mfma_f32_16x16x16_bf16 %0, %2, %6, %0\n\t"
      "v_mfma_f32_16x16x16_bf16 %0, %3, %7, %0\n\t"
      "v_mfma_f32_16x16x16_bf16 %0, %4, %8, %0"
      : "+v"(c)
      : "v"(a0), "v"(a1), "v"(a2), "v"(a3),
        "v"(b0), "v"(b1), "v"(b2), "v"(b3));
}

// Async global->LDS DMA, 16B per lane. LDS dest is wave-uniform base +
// lane*16 (hardware rule); global src is per-lane.
__device__ __forceinline__ void gload_lds16(const bf16* g, bf16* l) {
  __builtin_amdgcn_global_load_lds(
      (const __attribute__((address_space(1))) unsigned int*)g,
      (__attribute__((address_space(3))) unsigned int*)l, 16, 0, 0);
}

__device__ __forceinline__ void store_c(float* p, float v) { *p = v; }
__device__ __forceinline__ void store_c(bf16* p, float v) { *p = (bf16)v; }

// ---------------------------------------------------------------------------
// fp32 -> bf16 cast, 8 elems/thread
// ---------------------------------------------------------------------------
__global__ __launch_bounds__(256) void cast_bf16(const float* __restrict__ s,
                                                 bf16* __restrict__ d) {
  int i = blockIdx.x * 256 + threadIdx.x;
  float4 a = reinterpret_cast<const float4*>(s)[i * 2];
  float4 b = reinterpret_cast<const float4*>(s)[i * 2 + 1];
  bf16x8 v = {(bf16)a.x, (bf16)a.y, (bf16)a.z, (bf16)a.w,
              (bf16)b.x, (bf16)b.y, (bf16)b.z, (bf16)b.w};
  reinterpret_cast<bf16x8*>(d)[i] = v;
}

// ---------------------------------------------------------------------------
// gemm_bt v3 (R2-verified): 128x128 tile, BK=32, 2-phase double-buffer,
// global_load_lds staging, __launch_bounds__(256,4) (128-VGPR budget, no
// spill), 4-5 blocks/CU.
// ---------------------------------------------------------------------------
__device__ __forceinline__ void gemm_step(const bf16* AsL, const bf16* BsL,
                                          int wm, int wn, int l16, int quad,
                                          f32x4 (&acc)[4][4]) {
  bf16x8 af[4], bfr[4];
#pragma unroll
  for (int i = 0; i < 4; ++i)
    af[i] = *reinterpret_cast<const bf16x8*>(&AsL[(wm + i * 16 + l16) * 32 + quad * 8]);
#pragma unroll
  for (int j = 0; j < 4; ++j)
    bfr[j] = *reinterpret_cast<const bf16x8*>(&BsL[(wn + j * 16 + l16) * 32 + quad * 8]);
#pragma unroll
  for (int i = 0; i < 4; ++i)
#pragma unroll
    for (int j = 0; j < 4; ++j)
      acc[i][j] = mfma16(af[i], bfr[j], acc[i][j]);
}

template <typename TC>
__global__ __launch_bounds__(256, 4) void gemm_bt(const bf16* __restrict__ A,
                                                  const bf16* __restrict__ B,
                                                  TC* __restrict__ C,
                                                  int M, int N, int K) {
  __shared__ __align__(16) bf16 As[2][128 * 32];
  __shared__ __align__(16) bf16 Bs[2][128 * 32];

  const int tid  = threadIdx.x;
  const int wave = tid >> 6, lane = tid & 63;
  const int quad = lane >> 4, l16 = lane & 15;
  const int wm = (wave >> 1) * 64, wn = (wave & 1) * 64;
  const int n0 = blockIdx.x * 128, m0 = blockIdx.y * 128;

  const int r0 = tid >> 2;
  const int c0 = (tid & 3) * 8;
  const size_t aBase = (size_t)(m0 + r0) * K + c0;
  const size_t bBase = (size_t)(n0 + r0) * K + c0;
  const size_t rowK64 = (size_t)64 * K;

  const f32x4 zero = {0.f, 0.f, 0.f, 0.f};
  f32x4 acc[4][4];
#pragma unroll
  for (int i = 0; i < 4; ++i)
#pragma unroll
    for (int j = 0; j < 4; ++j) acc[i][j] = zero;

  gload_lds16(&A[aBase],          &As[0][tid * 8]);
  gload_lds16(&A[aBase + rowK64], &As[0][2048 + tid * 8]);
  gload_lds16(&B[bBase],          &Bs[0][tid * 8]);
  gload_lds16(&B[bBase + rowK64], &Bs[0][2048 + tid * 8]);
  __syncthreads();

  int cur = 0;
  for (int k0 = 32; k0 < K; k0 += 32) {
    const int nb = cur ^ 1;
    gload_lds16(&A[aBase + k0],          &As[nb][tid * 8]);
    gload_lds16(&A[aBase + rowK64 + k0], &As[nb][2048 + tid * 8]);
    gload_lds16(&B[bBase + k0],          &Bs[nb][tid * 8]);
    gload_lds16(&B[bBase + rowK64 + k0], &Bs[nb][2048 + tid * 8]);

    gemm_step(As[cur], Bs[cur], wm, wn, l16, quad, acc);

    __syncthreads();
    cur = nb;
  }
  gemm_step(As[cur], Bs[cur], wm, wn, l16, quad, acc);

#pragma unroll
  for (int i = 0; i < 4; ++i)
#pragma unroll
    for (int j = 0; j < 4; ++j)
#pragma unroll
      for (int r = 0; r < 4; ++r) {
        int row = m0 + wm + i * 16 + quad * 4 + r;
        int col = n0 + wn + j * 16 + l16;
        store_c(&C[(size_t)row * N + col], acc[i][j][r]);
      }
}

// ---------------------------------------------------------------------------
// norm_rope v2 (R3-verified): one block per token, 4 waves x 6 heads,
// shfl-only RMS reduce, sincos hoisted (12x fewer), 4096 dispatches.
// ---------------------------------------------------------------------------
__global__ __launch_bounds__(256) void norm_rope(const bf16* __restrict__ qkv,
                                                 const float* __restrict__ qw,
                                                 const float* __restrict__ kw,
                                                 const int* __restrict__ pos,
                                                 bf16* __restrict__ qn,
                                                 bf16* __restrict__ kn) {
  const int t = blockIdx.x;
  const int wv = threadIdx.x >> 6, l = threadIdx.x & 63;

  float inv = exp2f((float)l * (-19.93156856932417f / 64.0f));
  float fr = (float)pos[t] * inv;
  float sn, cs;
  sincosf(fr, &sn, &cs);
  const float qw1 = qw[l], qw2 = qw[l + 64];
  const float kw1 = kw[l], kw2 = kw[l + 64];
  const size_t rowb = (size_t)t * 4096;

#pragma unroll
  for (int i = 0; i < 6; ++i) {
    const int h = wv * 6 + i;            // 0..23, uniform per wave
    const bool isq = h < 16;
    const int col = isq ? h * 128 : 2048 + (h - 16) * 128;
    float x1 = (float)qkv[rowb + col + l];
    float x2 = (float)qkv[rowb + col + l + 64];
    float ss = x1 * x1 + x2 * x2;
#pragma unroll
    for (int o = 32; o >= 1; o >>= 1) ss += __shfl_xor(ss, o);
    float rms = rsqrtf(ss * (1.0f / 128.0f) + 1e-6f);
    float w1 = isq ? qw1 : kw1, w2 = isq ? qw2 : kw2;
    float xn1 = x1 * rms * w1, xn2 = x2 * rms * w2;
    float o1 = xn1 * cs - xn2 * sn;
    float o2 = xn2 * cs + xn1 * sn;
    if (isq) {
      qn[(size_t)t * 2048 + h * 128 + l] = (bf16)o1;
      qn[(size_t)t * 2048 + h * 128 + l + 64] = (bf16)o2;
    } else {
      kn[(size_t)t * 1024 + (h - 16) * 128 + l] = (bf16)o1;
      kn[(size_t)t * 1024 + (h - 16) * 128 + l + 64] = (bf16)o2;
    }
  }
}

// ---------------------------------------------------------------------------
// One-time V transpose — unchanged
// ---------------------------------------------------------------------------
__global__ __launch_bounds__(256) void transpose_v(const bf16* __restrict__ qkv,
                                                   bf16* __restrict__ vt) {
  __shared__ __align__(16) bf16 tile[128 * 72];
  const int t0 = blockIdx.x * 64, kvh = blockIdx.y;
  const int tid = threadIdx.x;
#pragma unroll
  for (int it = 0; it < 2; ++it) {
    int linear = it * 4096 + tid * 16;
    int r = linear >> 7, c = linear & 127;
    union { uint4 v; bf16 e[8]; } u0, u1;
    u0.v = *reinterpret_cast<const uint4*>(
        &qkv[(size_t)(t0 + r) * 4096 + 3072 + kvh * 128 + c]);
    u1.v = *reinterpret_cast<const uint4*>(
        &qkv[(size_t)(t0 + r) * 4096 + 3072 + kvh * 128 + c + 8]);
#pragma unroll
    for (int j = 0; j < 8; ++j) tile[(c + j) * 72 + r] = u0.e[j];
#pragma unroll
    for (int j = 0; j < 8; ++j) tile[(c + 8 + j) * 72 + r] = u1.e[j];
  }
  __syncthreads();
#pragma unroll
  for (int it = 0; it < 4; ++it) {
    int linear = it * 2048 + tid * 8;
    int d = linear >> 6, c = linear & 63;
    uint4 v = *reinterpret_cast<const uint4*>(&tile[d * 72 + c]);
    *reinterpret_cast<uint4*>(&vt[(size_t)(kvh * 128 + d) * 4096 + t0 + c]) = v;
  }
}

// ---------------------------------------------------------------------------
// Flash attention v8 (R3-verified, 154 us): grid (32,16), block 256, one
// head per block, q-tiles {bx, 63-bx} (65 k-tile units/block, perfect CU
// balance at 512 blocks = 2/CU). K/V staged via global_load_lds into
// double-buffered XOR-swizzled linear LDS; issue-next-before-compute so
// DMA latency hides under the compute phase. setprio around MFMA clusters
// (T5), defer-max (T13, THR=8).
// ---------------------------------------------------------------------------
__global__ __launch_bounds__(256, 2) void attn(const bf16* __restrict__ q,
                                               const bf16* __restrict__ k,
                                               const bf16* __restrict__ vt,
                                               bf16* __restrict__ out) {
  __shared__ __align__(16) bf16 Ks[2][64 * 128];  // [buf][kv row][dim] swizzled
  __shared__ __align__(16) bf16 Vs[2][128 * 64];  // [buf][dim][kv row] swizzled

  const int head = blockIdx.y, kvh = head >> 1;
  const int bx = blockIdx.x;

  const int tid = threadIdx.x;
  const int wave = tid >> 6, lane = tid & 63;
  const int quad = lane >> 4, l16 = lane & 15;
  const float cExp = 0.08838834764831845f * 1.4426950408889634f; // scale*log2e
  const f32x4 zero = {0.f, 0.f, 0.f, 0.f};

  int kSrc[4], vSrc[4];
#pragma unroll
  for (int it = 0; it < 4; ++it) {
    int r = (wave * 4 + it) * 4 + (lane >> 4);
    kSrc[it] = r * 1024 + kvh * 128 + (((lane & 15) ^ (r & 7)) << 3);
    int d = (wave * 4 + it) * 8 + (lane >> 3);
    vSrc[it] = (kvh * 128 + d) * 4096 + (((lane & 7) ^ (lane >> 3)) << 3);
  }

  const int kswz = (l16 & 7) << 3;
  int koff[4], voff[4];
#pragma unroll
  for (int s = 0; s < 4; ++s) {
    koff[s] = (s * 32 + quad * 8) ^ kswz;
    voff[s] = (s * 16 + quad * 4) ^ kswz;
  }

#pragma unroll
  for (int it = 0; it < 4; ++it) {
    gload_lds16(&k[kSrc[it]], &Ks[0][(wave * 4 + it) * 512]);
    gload_lds16(&vt[vSrc[it]], &Vs[0][(wave * 4 + it) * 512]);
  }
  int cur = 0;

#pragma unroll
  for (int phase = 0; phase < 2; ++phase) {
    const int qt = phase == 0 ? bx : 63 - bx;
    const int q0 = qt * 64;
    const int kend = q0 + 64;
    const int qrow = q0 + wave * 16 + l16;

    bf16x8 qf[4];
#pragma unroll
    for (int s = 0; s < 4; ++s)
      qf[s] = *reinterpret_cast<const bf16x8*>(
          &q[(size_t)qrow * 2048 + head * 128 + s * 32 + quad * 8]);

    f32x4 o_acc[8];
#pragma unroll
    for (int dt = 0; dt < 8; ++dt) o_acc[dt] = zero;
    float m_i = -3.0e38f, l_i = 0.f;

    for (int k0 = 0; k0 < kend; k0 += 64) {
      __syncthreads();

      int nk0 = -1;
      if (k0 + 64 < kend)     nk0 = k0 + 64;
      else if (phase == 0)    nk0 = 0;
      if (nk0 >= 0) {
#pragma unroll
        for (int it = 0; it < 4; ++it) {
          gload_lds16(&k[kSrc[it] + nk0 * 1024],
                      &Ks[cur ^ 1][(wave * 4 + it) * 512]);
          gload_lds16(&vt[vSrc[it] + nk0],
                      &Vs[cur ^ 1][(wave * 4 + it) * 512]);
        }
      }

      const bf16* KsL = Ks[cur];
      const bf16* VsL = Vs[cur];

      f32x4 s_acc[4];
      __builtin_amdgcn_s_setprio(1);
#pragma unroll
      for (int mt = 0; mt < 4; ++mt) {
        bf16x8 kf[4];
#pragma unroll
        for (int ks = 0; ks < 4; ++ks)
          kf[ks] = *reinterpret_cast<const bf16x8*>(
              &KsL[(mt * 16 + l16) * 128 + koff[ks]]);
        f32x4 sa = zero;
#pragma unroll
        for (int ks = 0; ks < 4; ++ks) sa = mfma16(kf[ks], qf[ks], sa);
        s_acc[mt] = sa;
      }
      __builtin_amdgcn_s_setprio(0);

      if (k0 == q0) {
        int tq = wave * 16 + l16;
#pragma unroll
        for (int mt = 0; mt < 4; ++mt)
#pragma unroll
          for (int r = 0; r < 4; ++r) {
            int tk = mt * 16 + quad * 4 + r;
            if (tk > tq) s_acc[mt][r] = -3.0e38f;
          }
      }

      {
        float mx = -3.0e38f;
#pragma unroll
        for (int mt = 0; mt < 4; ++mt)
#pragma unroll
          for (int r = 0; r < 4; ++r) mx = fmaxf(mx, s_acc[mt][r]);
        mx = fmaxf(mx, __shfl_xor(mx, 16));
        mx = fmaxf(mx, __shfl_xor(mx, 32));
        if (!__all((mx - m_i) * cExp <= 8.0f)) {
          float mn = fmaxf(m_i, mx);
          float al = exp2f((m_i - mn) * cExp);
          m_i = mn;
          l_i *= al;
#pragma unroll
          for (int dt = 0; dt < 8; ++dt)
#pragma unroll
            for (int r = 0; r < 4; ++r) o_acc[dt][r] *= al;
        }
        float nmc = -m_i * cExp;
        float rs = 0.f;
#pragma unroll
        for (int mt = 0; mt < 4; ++mt)
#pragma unroll
          for (int r = 0; r < 4; ++r) {
            float pe = exp2f(fmaf(s_acc[mt][r], cExp, nmc));
            s_acc[mt][r] = pe;
            rs += pe;
          }
        rs += __shfl_xor(rs, 16);
        rs += __shfl_xor(rs, 32);
        l_i += rs;
      }

      bf16x4 pb[4];
#pragma unroll
      for (int mt = 0; mt < 4; ++mt) {
        bf16x4 t;
#pragma unroll
        for (int r = 0; r < 4; ++r) t[r] = (bf16)s_acc[mt][r];
        pb[mt] = t;
      }

      __builtin_amdgcn_s_setprio(1);
#pragma unroll
      for (int dt = 0; dt < 8; ++dt) {
        const bf16* vrow = &VsL[(dt * 16 + l16) * 64];
        bf16x4 va0 = *reinterpret_cast<const bf16x4*>(&vrow[voff[0]]);
        bf16x4 va1 = *reinterpret_cast<const bf16x4*>(&vrow[voff[1]]);
        bf16x4 va2 = *reinterpret_cast<const bf16x4*>(&vrow[voff[2]]);
        bf16x4 va3 = *reinterpret_cast<const bf16x4*>(&vrow[voff[3]]);
        mfma16x16_chain4(va0, va1, va2, va3, pb[0], pb[1], pb[2], pb[3],
                         o_acc[dt]);
      }
      __builtin_amdgcn_s_setprio(0);
      cur ^= 1;
    }

    float rl = __builtin_amdgcn_rcpf(l_i);
#pragma unroll
    for (int dt = 0; dt < 8; ++dt) {
      bf16x4 ov;
#pragma unroll
      for (int r = 0; r < 4; ++r) ov[r] = (bf16)(o_acc[dt][r] * rl);
      *reinterpret_cast<bf16x4*>(
          &out[(size_t)qrow * 2048 + head * 128 + dt * 16 + quad * 4]) = ov;
    }
  }
}

// ---------------------------------------------------------------------------
extern "C" void kernel_launch(void* const* d_in, const int* in_sizes, int n_in,
                              void* d_out, int out_size, void* d_ws, size_t ws_size,
                              hipStream_t stream) {
  const float* hidden = (const float*)d_in[0];
  const float* qkv_w  = (const float*)d_in[1];
  const float* qnw    = (const float*)d_in[2];
  const float* knw    = (const float*)d_in[3];
  const float* o_w    = (const float*)d_in[4];
  const int*   pos    = (const int*)d_in[5];

  bf16* qkv = (bf16*)d_ws;                       // 4096*4096
  bf16* qn  = qkv + (size_t)4096 * 4096;         // 4096*2048
  bf16* kn  = qn  + (size_t)4096 * 2048;         // 4096*1024
  bf16* vt  = kn  + (size_t)4096 * 1024;         // 1024*4096
  bf16* ao  = vt  + (size_t)1024 * 4096;         // 4096*2048
  bf16* hb  = ao;   // bf16 hidden, dead before attn writes ao
  bf16* wq  = kn;   // bf16 qkv_w, dead before norm_rope/transpose write kn/vt
  bf16* wo  = qn;   // bf16 o_w, cast after attn (qn dead)
  float* out = (float*)d_out;

  cast_bf16<<<4096, 256, 0, stream>>>(hidden, hb);
  cast_bf16<<<4096, 256, 0, stream>>>(qkv_w, wq);
  gemm_bt<<<dim3(32, 32), 256, 0, stream>>>(hb, wq, qkv, 4096, 4096, 2048);
  norm_rope<<<4096, 256, 0, stream>>>(qkv, qnw, knw, pos, qn, kn);
  transpose_v<<<dim3(64, 8), 256, 0, stream>>>(qkv, vt);
  attn<<<dim3(32, 16), 256, 0, stream>>>(qn, kn, vt, ao);
  cast_bf16<<<2048, 256, 0, stream>>>(o_w, wo);
  gemm_bt<<<dim3(16, 32), 256, 0, stream>>>(ao, wo, out, 4096, 2048, 2048);
}

// Round 7
// 399.126 us; speedup vs baseline: 1.1875x; 1.0268x over previous
//
#include <hip/hip_runtime.h>
#include <hip/hip_bf16.h>
#include <math.h>

// ---------------------------------------------------------------------------
// Qwen3 attention block: T=4096, HIDDEN=2048, 16 Q heads, 8 KV heads,
// HEAD_DIM=128, rope theta 1e6, rms eps 1e-6, causal.
// fp32 in/out; bf16 internally for MFMA with fp32 accumulation.
// ---------------------------------------------------------------------------

typedef __bf16 bf16;
typedef __bf16 bf16x4 __attribute__((ext_vector_type(4)));
typedef __bf16 bf16x8 __attribute__((ext_vector_type(8)));
typedef float  f32x4  __attribute__((ext_vector_type(4)));

__device__ __forceinline__ f32x4 mfma16(bf16x8 a, bf16x8 b, f32x4 c) {
  return __builtin_amdgcn_mfma_f32_16x16x32_bf16(a, b, c, 0, 0, 0);
}

// 4 chained 16x16x16 bf16 MFMAs accumulating into one C/D quad.
__device__ __forceinline__ void mfma16x16_chain4(const bf16x4& a0, const bf16x4& a1,
                                                 const bf16x4& a2, const bf16x4& a3,
                                                 const bf16x4& b0, const bf16x4& b1,
                                                 const bf16x4& b2, const bf16x4& b3,
                                                 f32x4& c) {
  asm volatile(
      "s_nop 2\n\t"
      "v_mfma_f32_16x16x16_bf16 %0, %1, %5, %0\n\t"
      "v_mfma_f32_16x16x16_bf16 %0, %2, %6, %0\n\t"
      "v_mfma_f32_16x16x16_bf16 %0, %3, %7, %0\n\t"
      "v_mfma_f32_16x16x16_bf16 %0, %4, %8, %0"
      : "+v"(c)
      : "v"(a0), "v"(a1), "v"(a2), "v"(a3),
        "v"(b0), "v"(b1), "v"(b2), "v"(b3));
}

// Async global->LDS DMA, 16B per lane. LDS dest is wave-uniform base +
// lane*16 (hardware rule); global src is per-lane.
__device__ __forceinline__ void gload_lds16(const bf16* g, bf16* l) {
  __builtin_amdgcn_global_load_lds(
      (const __attribute__((address_space(1))) unsigned int*)g,
      (__attribute__((address_space(3))) unsigned int*)l, 16, 0, 0);
}

__device__ __forceinline__ void store_c(float* p, float v) { *p = v; }
__device__ __forceinline__ void store_c(bf16* p, float v) { *p = (bf16)v; }

// ---------------------------------------------------------------------------
// fp32 -> bf16 cast, 8 elems/thread
// ---------------------------------------------------------------------------
__global__ __launch_bounds__(256) void cast_bf16(const float* __restrict__ s,
                                                 bf16* __restrict__ d) {
  int i = blockIdx.x * 256 + threadIdx.x;
  float4 a = reinterpret_cast<const float4*>(s)[i * 2];
  float4 b = reinterpret_cast<const float4*>(s)[i * 2 + 1];
  bf16x8 v = {(bf16)a.x, (bf16)a.y, (bf16)a.z, (bf16)a.w,
              (bf16)b.x, (bf16)b.y, (bf16)b.z, (bf16)b.w};
  reinterpret_cast<bf16x8*>(d)[i] = v;
}

// ---------------------------------------------------------------------------
// gemm8ph: C[M][N] = A[M][K] @ B[N][K]^T, bf16 out. The 8-phase 256^2
// template (m201-derived): BK=64, 512 threads (2M x 4N waves, 128x64 out
// per wave), double-buffered 2x64KB LDS, 4 phases per K-tile.
//
// Per phase p (p = 0..3 within K-tile t):
//   ds_read A-frags fm in {2p,2p+1} (4x b128); at p0 also all B-frags (8x)
//   p0: stage A-halves of tile t+1 (4 gloads); p1: B-halves (4 gloads)
//     -> early issue so the boundary vmcnt(0) sees >=2-phase-old loads
//   s_barrier; sched_barrier(0)
//   setprio(1); 16 MFMA (2 fm x 4 fn x 2 ks); setprio(0)
//   p3: s_waitcnt vmcnt(0)   (once per K-tile; tile t+1's 8 loads, all
//       issued >=2 phases (~1200cy) ago -> effectively free)
//   s_barrier
//
// Race-freedom: staging targets buf[t+1&1], whose readers (tile t-1)
// finished at tile t-1's trailing barrier; every ds_read's value is
// consumed by an MFMA (compiler lgkmcnt) before the trailing barrier, so
// raw s_barrier (no waitcnt drain) is sufficient; boundary vmcnt(0)
// publishes the DMA before tile t+1's first ds_read.
//
// T2 swizzle (rows are 128B -> 16-way conflict unswizzled): 16B-chunk
// c' = c ^ (row&7). Applied on the pre-swizzled global source (rule #21:
// DMA dest stays linear) and on read offsets; koff = ((ks*4+quad) ^
// (l16&7))*8 distributes 64 lanes uniformly over the 8 conflict classes.
// T1 XCD swizzle on the 1D grid (nwg = 256, %8==0, bijective).
// ---------------------------------------------------------------------------
__global__ __launch_bounds__(512, 2) void gemm8ph(const bf16* __restrict__ A,
                                                  const bf16* __restrict__ B,
                                                  bf16* __restrict__ C,
                                                  int M, int N, int K) {
  __shared__ __align__(16) bf16 As[2][256 * 64];
  __shared__ __align__(16) bf16 Bs[2][256 * 64];

  const int tid  = threadIdx.x;
  const int lane = tid & 63, wid = tid >> 6;
  const int quad = lane >> 4, l16 = lane & 15;
  const int wr = wid >> 2, wc = wid & 3;  // 2 M-waves x 4 N-waves

  // XCD-aware bijective swizzle (nwg multiple of 8)
  const int nbx = N >> 8;
  const int nwg = (M >> 8) * nbx;
  const int cpx = nwg >> 3;
  const int swz = ((int)blockIdx.x & 7) * cpx + ((int)blockIdx.x >> 3);
  const int m0 = (swz / nbx) << 8;
  const int n0 = (swz % nbx) << 8;

  // staging: gload (h,g) covers rows h*128+g*64 + tid/8, LDS elems
  // h*8192+g*4096 + tid*8. Source col chunk pre-swizzled: (tid&7)^(row&7).
  const int srow = tid >> 3;                                  // 0..63
  const int scol = (((tid & 7) ^ (srow & 7)) << 3);           // pre-swizzled
  const bf16* aS = &A[(size_t)(m0 + srow) * K + scol];
  const bf16* bS = &B[(size_t)(n0 + srow) * K + scol];
  const size_t rk64 = (size_t)64 * K;

  // read-side swizzled k-offsets within a 64-elem row
  const int koff0 = ((quad)     ^ (l16 & 7)) << 3;            // ks=0
  const int koff1 = ((4 + quad) ^ (l16 & 7)) << 3;            // ks=1

  const f32x4 zero = {0.f, 0.f, 0.f, 0.f};
  f32x4 acc[8][4];
#pragma unroll
  for (int i = 0; i < 8; ++i)
#pragma unroll
    for (int j = 0; j < 4; ++j) acc[i][j] = zero;

  const int NT = K >> 6;

  // prologue: stage tile 0 into buf 0
  {
    gload_lds16(aS,            &As[0][tid * 8]);
    gload_lds16(aS + rk64,     &As[0][4096 + tid * 8]);
    gload_lds16(aS + 2 * rk64, &As[0][8192 + tid * 8]);
    gload_lds16(aS + 3 * rk64, &As[0][12288 + tid * 8]);
    gload_lds16(bS,            &Bs[0][tid * 8]);
    gload_lds16(bS + rk64,     &Bs[0][4096 + tid * 8]);
    gload_lds16(bS + 2 * rk64, &Bs[0][8192 + tid * 8]);
    gload_lds16(bS + 3 * rk64, &Bs[0][12288 + tid * 8]);
  }
  asm volatile("s_waitcnt vmcnt(0)" ::: "memory");
  __builtin_amdgcn_s_barrier();

  for (int t = 0; t < NT; ++t) {
    const int c = t & 1;
    const bf16* AsL = As[c];
    const bf16* BsL = Bs[c];
    const bool pre = (t + 1 < NT);
    const size_t nk = (size_t)(t + 1) * 64;
    bf16* An = As[c ^ 1];
    bf16* Bn = Bs[c ^ 1];

    bf16x8 bfv[4][2];

#pragma unroll
    for (int p = 0; p < 4; ++p) {
      // ---- ds_read this phase's fragments ----
      if (p == 0) {
#pragma unroll
        for (int fn = 0; fn < 4; ++fn) {
          const bf16* bp = &BsL[(wc * 64 + fn * 16 + l16) * 64];
          bfv[fn][0] = *reinterpret_cast<const bf16x8*>(&bp[koff0]);
          bfv[fn][1] = *reinterpret_cast<const bf16x8*>(&bp[koff1]);
        }
      }
      const bf16* ap0 = &AsL[(wr * 128 + (2 * p) * 16 + l16) * 64];
      const bf16* ap1 = ap0 + 16 * 64;
      bf16x8 a0k0 = *reinterpret_cast<const bf16x8*>(&ap0[koff0]);
      bf16x8 a0k1 = *reinterpret_cast<const bf16x8*>(&ap0[koff1]);
      bf16x8 a1k0 = *reinterpret_cast<const bf16x8*>(&ap1[koff0]);
      bf16x8 a1k1 = *reinterpret_cast<const bf16x8*>(&ap1[koff1]);

      // ---- stage next tile: A-halves at p0, B-halves at p1 ----
      if (p == 0 && pre) {
        gload_lds16(aS + nk,            &An[tid * 8]);
        gload_lds16(aS + rk64 + nk,     &An[4096 + tid * 8]);
        gload_lds16(aS + 2 * rk64 + nk, &An[8192 + tid * 8]);
        gload_lds16(aS + 3 * rk64 + nk, &An[12288 + tid * 8]);
      }
      if (p == 1 && pre) {
        gload_lds16(bS + nk,            &Bn[tid * 8]);
        gload_lds16(bS + rk64 + nk,     &Bn[4096 + tid * 8]);
        gload_lds16(bS + 2 * rk64 + nk, &Bn[8192 + tid * 8]);
        gload_lds16(bS + 3 * rk64 + nk, &Bn[12288 + tid * 8]);
      }

      __builtin_amdgcn_s_barrier();
      __builtin_amdgcn_sched_barrier(0);

      __builtin_amdgcn_s_setprio(1);
#pragma unroll
      for (int fn = 0; fn < 4; ++fn) {
        acc[2 * p][fn]     = mfma16(a0k1, bfv[fn][1],
                                    mfma16(a0k0, bfv[fn][0], acc[2 * p][fn]));
        acc[2 * p + 1][fn] = mfma16(a1k1, bfv[fn][1],
                                    mfma16(a1k0, bfv[fn][0], acc[2 * p + 1][fn]));
      }
      __builtin_amdgcn_s_setprio(0);

      if (p == 3 && pre) {
        asm volatile("s_waitcnt vmcnt(0)" ::: "memory");
      }
      __builtin_amdgcn_s_barrier();
    }
  }

#pragma unroll
  for (int fm = 0; fm < 8; ++fm)
#pragma unroll
    for (int fn = 0; fn < 4; ++fn)
#pragma unroll
      for (int r = 0; r < 4; ++r) {
        int row = m0 + wr * 128 + fm * 16 + quad * 4 + r;
        int col = n0 + wc * 64 + fn * 16 + l16;
        C[(size_t)row * N + col] = (bf16)acc[fm][fn][r];
      }
}

// ---------------------------------------------------------------------------
// gemm_bt v3 (R2-verified): 128x128 tile, BK=32, 2-phase double-buffer,
// global_load_lds staging. Kept for gemm2 (N=2048 -> 512 blocks = 2/CU;
// a 256-tile grid would be 128 blocks = half the CUs idle).
// ---------------------------------------------------------------------------
__device__ __forceinline__ void gemm_step(const bf16* AsL, const bf16* BsL,
                                          int wm, int wn, int l16, int quad,
                                          f32x4 (&acc)[4][4]) {
  bf16x8 af[4], bfr[4];
#pragma unroll
  for (int i = 0; i < 4; ++i)
    af[i] = *reinterpret_cast<const bf16x8*>(&AsL[(wm + i * 16 + l16) * 32 + quad * 8]);
#pragma unroll
  for (int j = 0; j < 4; ++j)
    bfr[j] = *reinterpret_cast<const bf16x8*>(&BsL[(wn + j * 16 + l16) * 32 + quad * 8]);
#pragma unroll
  for (int i = 0; i < 4; ++i)
#pragma unroll
    for (int j = 0; j < 4; ++j)
      acc[i][j] = mfma16(af[i], bfr[j], acc[i][j]);
}

template <typename TC>
__global__ __launch_bounds__(256, 4) void gemm_bt(const bf16* __restrict__ A,
                                                  const bf16* __restrict__ B,
                                                  TC* __restrict__ C,
                                                  int M, int N, int K) {
  __shared__ __align__(16) bf16 As[2][128 * 32];
  __shared__ __align__(16) bf16 Bs[2][128 * 32];

  const int tid  = threadIdx.x;
  const int wave = tid >> 6, lane = tid & 63;
  const int quad = lane >> 4, l16 = lane & 15;
  const int wm = (wave >> 1) * 64, wn = (wave & 1) * 64;
  const int n0 = blockIdx.x * 128, m0 = blockIdx.y * 128;

  const int r0 = tid >> 2;
  const int c0 = (tid & 3) * 8;
  const size_t aBase = (size_t)(m0 + r0) * K + c0;
  const size_t bBase = (size_t)(n0 + r0) * K + c0;
  const size_t rowK64 = (size_t)64 * K;

  const f32x4 zero = {0.f, 0.f, 0.f, 0.f};
  f32x4 acc[4][4];
#pragma unroll
  for (int i = 0; i < 4; ++i)
#pragma unroll
    for (int j = 0; j < 4; ++j) acc[i][j] = zero;

  gload_lds16(&A[aBase],          &As[0][tid * 8]);
  gload_lds16(&A[aBase + rowK64], &As[0][2048 + tid * 8]);
  gload_lds16(&B[bBase],          &Bs[0][tid * 8]);
  gload_lds16(&B[bBase + rowK64], &Bs[0][2048 + tid * 8]);
  __syncthreads();

  int cur = 0;
  for (int k0 = 32; k0 < K; k0 += 32) {
    const int nb = cur ^ 1;
    gload_lds16(&A[aBase + k0],          &As[nb][tid * 8]);
    gload_lds16(&A[aBase + rowK64 + k0], &As[nb][2048 + tid * 8]);
    gload_lds16(&B[bBase + k0],          &Bs[nb][tid * 8]);
    gload_lds16(&B[bBase + rowK64 + k0], &Bs[nb][2048 + tid * 8]);

    gemm_step(As[cur], Bs[cur], wm, wn, l16, quad, acc);

    __syncthreads();
    cur = nb;
  }
  gemm_step(As[cur], Bs[cur], wm, wn, l16, quad, acc);

#pragma unroll
  for (int i = 0; i < 4; ++i)
#pragma unroll
    for (int j = 0; j < 4; ++j)
#pragma unroll
      for (int r = 0; r < 4; ++r) {
        int row = m0 + wm + i * 16 + quad * 4 + r;
        int col = n0 + wn + j * 16 + l16;
        store_c(&C[(size_t)row * N + col], acc[i][j][r]);
      }
}

// ---------------------------------------------------------------------------
// norm_rope v2 (R3-verified) — unchanged
// ---------------------------------------------------------------------------
__global__ __launch_bounds__(256) void norm_rope(const bf16* __restrict__ qkv,
                                                 const float* __restrict__ qw,
                                                 const float* __restrict__ kw,
                                                 const int* __restrict__ pos,
                                                 bf16* __restrict__ qn,
                                                 bf16* __restrict__ kn) {
  const int t = blockIdx.x;
  const int wv = threadIdx.x >> 6, l = threadIdx.x & 63;

  float inv = exp2f((float)l * (-19.93156856932417f / 64.0f));
  float fr = (float)pos[t] * inv;
  float sn, cs;
  sincosf(fr, &sn, &cs);
  const float qw1 = qw[l], qw2 = qw[l + 64];
  const float kw1 = kw[l], kw2 = kw[l + 64];
  const size_t rowb = (size_t)t * 4096;

#pragma unroll
  for (int i = 0; i < 6; ++i) {
    const int h = wv * 6 + i;            // 0..23, uniform per wave
    const bool isq = h < 16;
    const int col = isq ? h * 128 : 2048 + (h - 16) * 128;
    float x1 = (float)qkv[rowb + col + l];
    float x2 = (float)qkv[rowb + col + l + 64];
    float ss = x1 * x1 + x2 * x2;
#pragma unroll
    for (int o = 32; o >= 1; o >>= 1) ss += __shfl_xor(ss, o);
    float rms = rsqrtf(ss * (1.0f / 128.0f) + 1e-6f);
    float w1 = isq ? qw1 : kw1, w2 = isq ? qw2 : kw2;
    float xn1 = x1 * rms * w1, xn2 = x2 * rms * w2;
    float o1 = xn1 * cs - xn2 * sn;
    float o2 = xn2 * cs + xn1 * sn;
    if (isq) {
      qn[(size_t)t * 2048 + h * 128 + l] = (bf16)o1;
      qn[(size_t)t * 2048 + h * 128 + l + 64] = (bf16)o2;
    } else {
      kn[(size_t)t * 1024 + (h - 16) * 128 + l] = (bf16)o1;
      kn[(size_t)t * 1024 + (h - 16) * 128 + l + 64] = (bf16)o2;
    }
  }
}

// ---------------------------------------------------------------------------
// One-time V transpose — unchanged
// ---------------------------------------------------------------------------
__global__ __launch_bounds__(256) void transpose_v(const bf16* __restrict__ qkv,
                                                   bf16* __restrict__ vt) {
  __shared__ __align__(16) bf16 tile[128 * 72];
  const int t0 = blockIdx.x * 64, kvh = blockIdx.y;
  const int tid = threadIdx.x;
#pragma unroll
  for (int it = 0; it < 2; ++it) {
    int linear = it * 4096 + tid * 16;
    int r = linear >> 7, c = linear & 127;
    union { uint4 v; bf16 e[8]; } u0, u1;
    u0.v = *reinterpret_cast<const uint4*>(
        &qkv[(size_t)(t0 + r) * 4096 + 3072 + kvh * 128 + c]);
    u1.v = *reinterpret_cast<const uint4*>(
        &qkv[(size_t)(t0 + r) * 4096 + 3072 + kvh * 128 + c + 8]);
#pragma unroll
    for (int j = 0; j < 8; ++j) tile[(c + j) * 72 + r] = u0.e[j];
#pragma unroll
    for (int j = 0; j < 8; ++j) tile[(c + 8 + j) * 72 + r] = u1.e[j];
  }
  __syncthreads();
#pragma unroll
  for (int it = 0; it < 4; ++it) {
    int linear = it * 2048 + tid * 8;
    int d = linear >> 6, c = linear & 63;
    uint4 v = *reinterpret_cast<const uint4*>(&tile[d * 72 + c]);
    *reinterpret_cast<uint4*>(&vt[(size_t)(kvh * 128 + d) * 4096 + t0 + c]) = v;
  }
}

// ---------------------------------------------------------------------------
// Flash attention v8 (R3/R5-verified, 153 us) — unchanged
// ---------------------------------------------------------------------------
__global__ __launch_bounds__(256, 2) void attn(const bf16* __restrict__ q,
                                               const bf16* __restrict__ k,
                                               const bf16* __restrict__ vt,
                                               bf16* __restrict__ out) {
  __shared__ __align__(16) bf16 Ks[2][64 * 128];  // [buf][kv row][dim] swizzled
  __shared__ __align__(16) bf16 Vs[2][128 * 64];  // [buf][dim][kv row] swizzled

  const int head = blockIdx.y, kvh = head >> 1;
  const int bx = blockIdx.x;

  const int tid = threadIdx.x;
  const int wave = tid >> 6, lane = tid & 63;
  const int quad = lane >> 4, l16 = lane & 15;
  const float cExp = 0.08838834764831845f * 1.4426950408889634f; // scale*log2e
  const f32x4 zero = {0.f, 0.f, 0.f, 0.f};

  int kSrc[4], vSrc[4];
#pragma unroll
  for (int it = 0; it < 4; ++it) {
    int r = (wave * 4 + it) * 4 + (lane >> 4);
    kSrc[it] = r * 1024 + kvh * 128 + (((lane & 15) ^ (r & 7)) << 3);
    int d = (wave * 4 + it) * 8 + (lane >> 3);
    vSrc[it] = (kvh * 128 + d) * 4096 + (((lane & 7) ^ (lane >> 3)) << 3);
  }

  const int kswz = (l16 & 7) << 3;
  int koff[4], voff[4];
#pragma unroll
  for (int s = 0; s < 4; ++s) {
    koff[s] = (s * 32 + quad * 8) ^ kswz;
    voff[s] = (s * 16 + quad * 4) ^ kswz;
  }

#pragma unroll
  for (int it = 0; it < 4; ++it) {
    gload_lds16(&k[kSrc[it]], &Ks[0][(wave * 4 + it) * 512]);
    gload_lds16(&vt[vSrc[it]], &Vs[0][(wave * 4 + it) * 512]);
  }
  int cur = 0;

#pragma unroll
  for (int phase = 0; phase < 2; ++phase) {
    const int qt = phase == 0 ? bx : 63 - bx;
    const int q0 = qt * 64;
    const int kend = q0 + 64;
    const int qrow = q0 + wave * 16 + l16;

    bf16x8 qf[4];
#pragma unroll
    for (int s = 0; s < 4; ++s)
      qf[s] = *reinterpret_cast<const bf16x8*>(
          &q[(size_t)qrow * 2048 + head * 128 + s * 32 + quad * 8]);

    f32x4 o_acc[8];
#pragma unroll
    for (int dt = 0; dt < 8; ++dt) o_acc[dt] = zero;
    float m_i = -3.0e38f, l_i = 0.f;

    for (int k0 = 0; k0 < kend; k0 += 64) {
      __syncthreads();

      int nk0 = -1;
      if (k0 + 64 < kend)     nk0 = k0 + 64;
      else if (phase == 0)    nk0 = 0;
      if (nk0 >= 0) {
#pragma unroll
        for (int it = 0; it < 4; ++it) {
          gload_lds16(&k[kSrc[it] + nk0 * 1024],
                      &Ks[cur ^ 1][(wave * 4 + it) * 512]);
          gload_lds16(&vt[vSrc[it] + nk0],
                      &Vs[cur ^ 1][(wave * 4 + it) * 512]);
        }
      }

      const bf16* KsL = Ks[cur];
      const bf16* VsL = Vs[cur];

      f32x4 s_acc[4];
      __builtin_amdgcn_s_setprio(1);
#pragma unroll
      for (int mt = 0; mt < 4; ++mt) {
        bf16x8 kf[4];
#pragma unroll
        for (int ks = 0; ks < 4; ++ks)
          kf[ks] = *reinterpret_cast<const bf16x8*>(
              &KsL[(mt * 16 + l16) * 128 + koff[ks]]);
        f32x4 sa = zero;
#pragma unroll
        for (int ks = 0; ks < 4; ++ks) sa = mfma16(kf[ks], qf[ks], sa);
        s_acc[mt] = sa;
      }
      __builtin_amdgcn_s_setprio(0);

      if (k0 == q0) {
        int tq = wave * 16 + l16;
#pragma unroll
        for (int mt = 0; mt < 4; ++mt)
#pragma unroll
          for (int r = 0; r < 4; ++r) {
            int tk = mt * 16 + quad * 4 + r;
            if (tk > tq) s_acc[mt][r] = -3.0e38f;
          }
      }

      {
        float mx = -3.0e38f;
#pragma unroll
        for (int mt = 0; mt < 4; ++mt)
#pragma unroll
          for (int r = 0; r < 4; ++r) mx = fmaxf(mx, s_acc[mt][r]);
        mx = fmaxf(mx, __shfl_xor(mx, 16));
        mx = fmaxf(mx, __shfl_xor(mx, 32));
        if (!__all((mx - m_i) * cExp <= 8.0f)) {
          float mn = fmaxf(m_i, mx);
          float al = exp2f((m_i - mn) * cExp);
          m_i = mn;
          l_i *= al;
#pragma unroll
          for (int dt = 0; dt < 8; ++dt)
#pragma unroll
            for (int r = 0; r < 4; ++r) o_acc[dt][r] *= al;
        }
        float nmc = -m_i * cExp;
        float rs = 0.f;
#pragma unroll
        for (int mt = 0; mt < 4; ++mt)
#pragma unroll
          for (int r = 0; r < 4; ++r) {
            float pe = exp2f(fmaf(s_acc[mt][r], cExp, nmc));
            s_acc[mt][r] = pe;
            rs += pe;
          }
        rs += __shfl_xor(rs, 16);
        rs += __shfl_xor(rs, 32);
        l_i += rs;
      }

      bf16x4 pb[4];
#pragma unroll
      for (int mt = 0; mt < 4; ++mt) {
        bf16x4 t;
#pragma unroll
        for (int r = 0; r < 4; ++r) t[r] = (bf16)s_acc[mt][r];
        pb[mt] = t;
      }

      __builtin_amdgcn_s_setprio(1);
#pragma unroll
      for (int dt = 0; dt < 8; ++dt) {
        const bf16* vrow = &VsL[(dt * 16 + l16) * 64];
        bf16x4 va0 = *reinterpret_cast<const bf16x4*>(&vrow[voff[0]]);
        bf16x4 va1 = *reinterpret_cast<const bf16x4*>(&vrow[voff[1]]);
        bf16x4 va2 = *reinterpret_cast<const bf16x4*>(&vrow[voff[2]]);
        bf16x4 va3 = *reinterpret_cast<const bf16x4*>(&vrow[voff[3]]);
        mfma16x16_chain4(va0, va1, va2, va3, pb[0], pb[1], pb[2], pb[3],
                         o_acc[dt]);
      }
      __builtin_amdgcn_s_setprio(0);
      cur ^= 1;
    }

    float rl = __builtin_amdgcn_rcpf(l_i);
#pragma unroll
    for (int dt = 0; dt < 8; ++dt) {
      bf16x4 ov;
#pragma unroll
      for (int r = 0; r < 4; ++r) ov[r] = (bf16)(o_acc[dt][r] * rl);
      *reinterpret_cast<bf16x4*>(
          &out[(size_t)qrow * 2048 + head * 128 + dt * 16 + quad * 4]) = ov;
    }
  }
}

// ---------------------------------------------------------------------------
extern "C" void kernel_launch(void* const* d_in, const int* in_sizes, int n_in,
                              void* d_out, int out_size, void* d_ws, size_t ws_size,
                              hipStream_t stream) {
  const float* hidden = (const float*)d_in[0];
  const float* qkv_w  = (const float*)d_in[1];
  const float* qnw    = (const float*)d_in[2];
  const float* knw    = (const float*)d_in[3];
  const float* o_w    = (const float*)d_in[4];
  const int*   pos    = (const int*)d_in[5];

  bf16* qkv = (bf16*)d_ws;                       // 4096*4096
  bf16* qn  = qkv + (size_t)4096 * 4096;         // 4096*2048
  bf16* kn  = qn  + (size_t)4096 * 2048;         // 4096*1024
  bf16* vt  = kn  + (size_t)4096 * 1024;         // 1024*4096
  bf16* ao  = vt  + (size_t)1024 * 4096;         // 4096*2048
  bf16* hb  = ao;   // bf16 hidden, dead before attn writes ao
  bf16* wq  = kn;   // bf16 qkv_w, dead before norm_rope/transpose write kn/vt
  bf16* wo  = qn;   // bf16 o_w, cast after attn (qn dead)
  float* out = (float*)d_out;

  cast_bf16<<<4096, 256, 0, stream>>>(hidden, hb);
  cast_bf16<<<4096, 256, 0, stream>>>(qkv_w, wq);
  gemm8ph<<<256, 512, 0, stream>>>(hb, wq, qkv, 4096, 4096, 2048);
  norm_rope<<<4096, 256, 0, stream>>>(qkv, qnw, knw, pos, qn, kn);
  transpose_v<<<dim3(64, 8), 256, 0, stream>>>(qkv, vt);
  attn<<<dim3(32, 16), 256, 0, stream>>>(qn, kn, vt, ao);
  cast_bf16<<<2048, 256, 0, stream>>>(o_w, wo);
  gemm_bt<<<dim3(16, 32), 256, 0, stream>>>(ao, wo, out, 4096, 2048, 2048);
}